// Round 1
// baseline (555.558 us; speedup 1.0000x reference)
//
#include <hip/hip_runtime.h>
#include <hip/hip_bf16.h>
#include <math.h>

#define H_HEADS 16
#define DMODEL  1024
#define DHEAD   64
#define LSEQ    1024
#define CHUNK   64
#define EPS_F   1e-6f

// =====================================================================
// GEMM core: C = X @ W^T   (X: [M,K] row-major, W: [N,K] row-major)
// tile 128x128, BK=32, 256 threads, 8x8 micro-tile per thread.
// =====================================================================

// Fused QKV projection. grid = (N/128, M/128, 3); z selects Q/K/V.
// Q,K: y = acc * scale; out = elu(y)+1  ( = y+1 if y>0 else exp(y) )
// V:   out = acc
// Output layout: [B, H, L, d]  (b = m>>10, l = m&1023, h = n>>6, e = n&63)
__global__ __launch_bounds__(256)
void proj_kernel(const float* __restrict__ q_in, const float* __restrict__ k_in,
                 const float* __restrict__ v_in,
                 const float* __restrict__ Wq, const float* __restrict__ Wk,
                 const float* __restrict__ Wv,
                 float* __restrict__ qp, float* __restrict__ kp,
                 float* __restrict__ vp)
{
    const int z = blockIdx.z;
    const float* X = (z == 0) ? q_in : (z == 1) ? k_in : v_in;
    const float* W = (z == 0) ? Wq   : (z == 1) ? Wk   : Wv;
    float* out     = (z == 0) ? qp   : (z == 1) ? kp   : vp;

    __shared__ float Xs[32][128];
    __shared__ float Ws[32][128];

    const int tid = threadIdx.x;
    const int tx = tid & 15, ty = tid >> 4;
    const int m0 = blockIdx.y * 128;
    const int n0 = blockIdx.x * 128;
    const int K = DMODEL;

    float acc[8][8];
#pragma unroll
    for (int i = 0; i < 8; ++i)
#pragma unroll
        for (int j = 0; j < 8; ++j) acc[i][j] = 0.f;

    for (int kt = 0; kt < K; kt += 32) {
#pragma unroll
        for (int i = 0; i < 4; ++i) {
            int f = tid + i * 256;
            int row = f >> 3, kq = f & 7;
            float4 xv = *(const float4*)(X + (size_t)(m0 + row) * K + kt + kq * 4);
            Xs[kq * 4 + 0][row] = xv.x; Xs[kq * 4 + 1][row] = xv.y;
            Xs[kq * 4 + 2][row] = xv.z; Xs[kq * 4 + 3][row] = xv.w;
            float4 wv = *(const float4*)(W + (size_t)(n0 + row) * K + kt + kq * 4);
            Ws[kq * 4 + 0][row] = wv.x; Ws[kq * 4 + 1][row] = wv.y;
            Ws[kq * 4 + 2][row] = wv.z; Ws[kq * 4 + 3][row] = wv.w;
        }
        __syncthreads();
#pragma unroll 4
        for (int k = 0; k < 32; ++k) {
            float a[8], b[8];
            *(float4*)&a[0] = *(const float4*)&Xs[k][ty * 8];
            *(float4*)&a[4] = *(const float4*)&Xs[k][ty * 8 + 4];
            *(float4*)&b[0] = *(const float4*)&Ws[k][tx * 8];
            *(float4*)&b[4] = *(const float4*)&Ws[k][tx * 8 + 4];
#pragma unroll
            for (int i = 0; i < 8; ++i)
#pragma unroll
                for (int j = 0; j < 8; ++j)
                    acc[i][j] = fmaf(a[i], b[j], acc[i][j]);
        }
        __syncthreads();
    }

    const float sc = (z < 2) ? 0.125f : 1.f;   // d^-0.5 = 1/8
#pragma unroll
    for (int i = 0; i < 8; ++i) {
        int m = m0 + ty * 8 + i;
        int b = m >> 10, l = m & 1023;
#pragma unroll
        for (int j = 0; j < 8; ++j) {
            int n = n0 + tx * 8 + j;
            int h = n >> 6, e = n & 63;
            float y = acc[i][j] * sc;
            float pv = (z < 2) ? ((y > 0.f) ? y + 1.f : expf(y)) : y;
            out[(((size_t)(b * H_HEADS + h) * LSEQ) + l) * DHEAD + e] = pv;
        }
    }
}

// Final GEMM: out = att @ Wo^T, plain row-major [M, N] store.
__global__ __launch_bounds__(256)
void gemm_out_kernel(const float* __restrict__ X, const float* __restrict__ W,
                     float* __restrict__ out, int M)
{
    __shared__ float Xs[32][128];
    __shared__ float Ws[32][128];

    const int tid = threadIdx.x;
    const int tx = tid & 15, ty = tid >> 4;
    const int m0 = blockIdx.y * 128;
    const int n0 = blockIdx.x * 128;
    const int K = DMODEL, N = DMODEL;

    float acc[8][8];
#pragma unroll
    for (int i = 0; i < 8; ++i)
#pragma unroll
        for (int j = 0; j < 8; ++j) acc[i][j] = 0.f;

    for (int kt = 0; kt < K; kt += 32) {
#pragma unroll
        for (int i = 0; i < 4; ++i) {
            int f = tid + i * 256;
            int row = f >> 3, kq = f & 7;
            float4 xv = *(const float4*)(X + (size_t)(m0 + row) * K + kt + kq * 4);
            Xs[kq * 4 + 0][row] = xv.x; Xs[kq * 4 + 1][row] = xv.y;
            Xs[kq * 4 + 2][row] = xv.z; Xs[kq * 4 + 3][row] = xv.w;
            float4 wv = *(const float4*)(W + (size_t)(n0 + row) * K + kt + kq * 4);
            Ws[kq * 4 + 0][row] = wv.x; Ws[kq * 4 + 1][row] = wv.y;
            Ws[kq * 4 + 2][row] = wv.z; Ws[kq * 4 + 3][row] = wv.w;
        }
        __syncthreads();
#pragma unroll 4
        for (int k = 0; k < 32; ++k) {
            float a[8], b[8];
            *(float4*)&a[0] = *(const float4*)&Xs[k][ty * 8];
            *(float4*)&a[4] = *(const float4*)&Xs[k][ty * 8 + 4];
            *(float4*)&b[0] = *(const float4*)&Ws[k][tx * 8];
            *(float4*)&b[4] = *(const float4*)&Ws[k][tx * 8 + 4];
#pragma unroll
            for (int i = 0; i < 8; ++i)
#pragma unroll
                for (int j = 0; j < 8; ++j)
                    acc[i][j] = fmaf(a[i], b[j], acc[i][j]);
        }
        __syncthreads();
    }

#pragma unroll
    for (int i = 0; i < 8; ++i) {
        int m = m0 + ty * 8 + i;
#pragma unroll
        for (int j = 0; j < 8; ++j) {
            int n = n0 + tx * 8 + j;
            out[(size_t)m * N + n] = acc[i][j];
        }
    }
}

// =====================================================================
// Per-chunk KV outer-product sums: S_c[i][j] = sum_{t in chunk} kp[t][i]*v[t][j]
// z_c[i] = sum_{t in chunk} kp[t][i].  grid = (NC, B*H), block 256.
// =====================================================================
__global__ __launch_bounds__(256)
void chunk_kv_kernel(const float* __restrict__ kp, const float* __restrict__ vp,
                     float* __restrict__ S, float* __restrict__ z, int NC)
{
    const int c = blockIdx.x, bh = blockIdx.y;
    const int tid = threadIdx.x;
    const int txx = tid & 15, tyy = tid >> 4;

    __shared__ float ks[64][64];
    __shared__ float vs[64][64];

    const size_t base = ((size_t)bh * LSEQ + (size_t)c * CHUNK) * DHEAD;
#pragma unroll
    for (int i = 0; i < 4; ++i) {
        int f = tid + i * 256;
        int row = f >> 4, qd = (f & 15) * 4;
        *(float4*)&ks[row][qd] = *(const float4*)(kp + base + row * 64 + qd);
        *(float4*)&vs[row][qd] = *(const float4*)(vp + base + row * 64 + qd);
    }
    __syncthreads();

    float acc[4][4];
#pragma unroll
    for (int i = 0; i < 4; ++i)
#pragma unroll
        for (int j = 0; j < 4; ++j) acc[i][j] = 0.f;

    for (int t = 0; t < 64; ++t) {
        float a[4];
        float4 b4 = *(const float4*)&vs[t][txx * 4];
#pragma unroll
        for (int ii = 0; ii < 4; ++ii) a[ii] = ks[t][tyy * 4 + ii];
#pragma unroll
        for (int ii = 0; ii < 4; ++ii) {
            acc[ii][0] = fmaf(a[ii], b4.x, acc[ii][0]);
            acc[ii][1] = fmaf(a[ii], b4.y, acc[ii][1]);
            acc[ii][2] = fmaf(a[ii], b4.z, acc[ii][2]);
            acc[ii][3] = fmaf(a[ii], b4.w, acc[ii][3]);
        }
    }

    const size_t sbase = ((size_t)bh * NC + c) * (DHEAD * DHEAD);
#pragma unroll
    for (int ii = 0; ii < 4; ++ii) {
        int i = tyy * 4 + ii;
        *(float4*)&S[sbase + (size_t)i * 64 + txx * 4] =
            make_float4(acc[ii][0], acc[ii][1], acc[ii][2], acc[ii][3]);
    }

    if (tid < 64) {
        float s = 0.f;
        for (int t = 0; t < 64; ++t) s += ks[t][tid];
        z[((size_t)bh * NC + c) * 64 + tid] = s;
    }
}

// =====================================================================
// Exclusive prefix over chunks (in place). grid = B*H, block 256.
// =====================================================================
__global__ __launch_bounds__(256)
void prefix_kernel(float* __restrict__ S, float* __restrict__ z, int NC)
{
    const int bh = blockIdx.x;
    const int tid = threadIdx.x;
    for (int e = tid; e < DHEAD * DHEAD; e += 256) {
        float run = 0.f;
        for (int c = 0; c < NC; ++c) {
            size_t idx = ((size_t)bh * NC + c) * (DHEAD * DHEAD) + e;
            float tmp = S[idx];
            S[idx] = run;
            run += tmp;
        }
    }
    if (tid < 64) {
        float run = 0.f;
        for (int c = 0; c < NC; ++c) {
            size_t idx = ((size_t)bh * NC + c) * 64 + tid;
            float tmp = z[idx];
            z[idx] = run;
            run += tmp;
        }
    }
}

// =====================================================================
// Per-chunk causal attention output.
// out[t][e] = ( qp_t . Sprev[:,e] + sum_{s<=t} (qp_t . kp_s) v_s[e] )
//             / ( qp_t . zprev + sum_{s<=t} qp_t . kp_s + eps )
// grid = (NC, B*H), block 256. Stores att in [B, L, D] layout.
// =====================================================================
__global__ __launch_bounds__(256)
void attn_chunk_kernel(const float* __restrict__ qp, const float* __restrict__ kp,
                       const float* __restrict__ vp,
                       const float* __restrict__ Spre, const float* __restrict__ zpre,
                       float* __restrict__ att, int NC)
{
    const int c = blockIdx.x, bh = blockIdx.y;
    const int b = bh >> 4, h = bh & 15;
    const int tid = threadIdx.x;
    const int txx = tid & 15, tyy = tid >> 4;

    __shared__ float qs[64][64];
    __shared__ float ks[64][64];   // Kp, later reused for V
    __shared__ float ss[64][64];   // Sprev
    __shared__ float ps[64][64];   // masked P

    const size_t base = ((size_t)bh * LSEQ + (size_t)c * CHUNK) * DHEAD;
    const size_t sbase = ((size_t)bh * NC + c) * (DHEAD * DHEAD);
    const float* zp = zpre + ((size_t)bh * NC + c) * 64;

#pragma unroll
    for (int i = 0; i < 4; ++i) {
        int f = tid + i * 256;
        int row = f >> 4, qd = (f & 15) * 4;
        *(float4*)&qs[row][qd] = *(const float4*)(qp + base + row * 64 + qd);
        *(float4*)&ks[row][qd] = *(const float4*)(kp + base + row * 64 + qd);
        *(float4*)&ss[row][qd] = *(const float4*)(Spre + sbase + row * 64 + qd);
    }
    __syncthreads();

    float oacc[4][4], pacc[4][4], den[4];
#pragma unroll
    for (int i = 0; i < 4; ++i) {
        den[i] = 0.f;
#pragma unroll
        for (int j = 0; j < 4; ++j) { oacc[i][j] = 0.f; pacc[i][j] = 0.f; }
    }

    for (int k = 0; k < 64; ++k) {
        float a[4], bb[4];
        float4 s4 = *(const float4*)&ss[k][txx * 4];
        float zk = zp[k];
#pragma unroll
        for (int ii = 0; ii < 4; ++ii) a[ii] = qs[tyy * 4 + ii][k];
#pragma unroll
        for (int jj = 0; jj < 4; ++jj) bb[jj] = ks[txx * 4 + jj][k];
#pragma unroll
        for (int ii = 0; ii < 4; ++ii) {
            den[ii] = fmaf(a[ii], zk, den[ii]);
            oacc[ii][0] = fmaf(a[ii], s4.x, oacc[ii][0]);
            oacc[ii][1] = fmaf(a[ii], s4.y, oacc[ii][1]);
            oacc[ii][2] = fmaf(a[ii], s4.z, oacc[ii][2]);
            oacc[ii][3] = fmaf(a[ii], s4.w, oacc[ii][3]);
#pragma unroll
            for (int jj = 0; jj < 4; ++jj)
                pacc[ii][jj] = fmaf(a[ii], bb[jj], pacc[ii][jj]);
        }
    }

#pragma unroll
    for (int ii = 0; ii < 4; ++ii) {
        int t = tyy * 4 + ii;
#pragma unroll
        for (int jj = 0; jj < 4; ++jj) {
            int s = txx * 4 + jj;
            ps[t][s] = (s <= t) ? pacc[ii][jj] : 0.f;
        }
    }
    __syncthreads();   // everyone done with ks (Kp) and ps is complete

    // reload V into ks
#pragma unroll
    for (int i = 0; i < 4; ++i) {
        int f = tid + i * 256;
        int row = f >> 4, qd = (f & 15) * 4;
        *(float4*)&ks[row][qd] = *(const float4*)(vp + base + row * 64 + qd);
    }
    __syncthreads();

    for (int s = 0; s < 64; ++s) {
        float4 v4 = *(const float4*)&ks[s][txx * 4];
#pragma unroll
        for (int ii = 0; ii < 4; ++ii) {
            float p = ps[tyy * 4 + ii][s];
            den[ii] += p;
            oacc[ii][0] = fmaf(p, v4.x, oacc[ii][0]);
            oacc[ii][1] = fmaf(p, v4.y, oacc[ii][1]);
            oacc[ii][2] = fmaf(p, v4.z, oacc[ii][2]);
            oacc[ii][3] = fmaf(p, v4.w, oacc[ii][3]);
        }
    }

#pragma unroll
    for (int ii = 0; ii < 4; ++ii) {
        int t = tyy * 4 + ii;
        int l = c * CHUNK + t;
        float inv = 1.f / (den[ii] + EPS_F);
#pragma unroll
        for (int jj = 0; jj < 4; ++jj) {
            int e = txx * 4 + jj;
            att[((size_t)b * LSEQ + l) * DMODEL + h * DHEAD + e] = oacc[ii][jj] * inv;
        }
    }
}

// =====================================================================
extern "C" void kernel_launch(void* const* d_in, const int* in_sizes, int n_in,
                              void* d_out, int out_size, void* d_ws, size_t ws_size,
                              hipStream_t stream)
{
    const float* query = (const float*)d_in[0];
    const float* key_  = (const float*)d_in[1];
    const float* value = (const float*)d_in[2];
    const float* Wq = (const float*)d_in[3];
    const float* Wk = (const float*)d_in[4];
    const float* Wv = (const float*)d_in[5];
    const float* Wo = (const float*)d_in[6];
    float* out = (float*)d_out;

    const int B  = in_sizes[0] / (LSEQ * DMODEL);   // 2
    const int M  = B * LSEQ;                        // 2048
    const int BH = B * H_HEADS;                     // 32
    const int NC = LSEQ / CHUNK;                    // 16

    float* ws  = (float*)d_ws;
    float* qp  = ws;
    float* kp  = qp  + (size_t)BH * LSEQ * DHEAD;
    float* vp  = kp  + (size_t)BH * LSEQ * DHEAD;
    float* att = vp  + (size_t)BH * LSEQ * DHEAD;
    float* S   = att + (size_t)M * DMODEL;
    float* z   = S   + (size_t)BH * NC * DHEAD * DHEAD;

    dim3 blk(256);
    proj_kernel<<<dim3(DMODEL / 128, M / 128, 3), blk, 0, stream>>>(
        query, key_, value, Wq, Wk, Wv, qp, kp, vp);
    chunk_kv_kernel<<<dim3(NC, BH), blk, 0, stream>>>(kp, vp, S, z, NC);
    prefix_kernel<<<dim3(BH), blk, 0, stream>>>(S, z, NC);
    attn_chunk_kernel<<<dim3(NC, BH), blk, 0, stream>>>(qp, kp, vp, S, z, att, NC);
    gemm_out_kernel<<<dim3(DMODEL / 128, M / 128), blk, 0, stream>>>(att, Wo, out, M);
}

// Round 2
// 194.340 us; speedup vs baseline: 2.8587x; 2.8587x over previous
//
#include <hip/hip_runtime.h>
#include <hip/hip_bf16.h>
#include <math.h>

#define H_HEADS 16
#define DMODEL  1024
#define DHEAD   64
#define LSEQ    1024
#define CHUNK   64
#define EPS_F   1e-6f

typedef __attribute__((ext_vector_type(8))) short bf16x8;   // 8 bf16 = 4 VGPRs
typedef __attribute__((ext_vector_type(4))) float f32x4;    // MFMA 16x16 accumulator

__device__ inline unsigned short f2bf(float f) {
    unsigned int u = __float_as_uint(f);
    u += 0x7FFF + ((u >> 16) & 1);          // round-to-nearest-even
    return (unsigned short)(u >> 16);
}

#define LDA 40   // LDS row stride in bf16 elems (80B = 16B-aligned, conflict-reduced)

// =====================================================================
// bf16 MFMA GEMM: C = X @ W^T.  X:[M,K] fp32 row-major, W:[N,K] fp32 row-major.
// 128x128 tile, BK=32, 256 thr = 4 waves (2x2 of 64x64), 16x16x32 MFMA.
// Reg-staging converts fp32->bf16 inline; LDS padded to stride 40.
// PROJ=true: blockIdx.z selects Q/K/V; epilogue applies scale+elu+1 (z<2)
//            and stores [B,H,L,d].  PROJ=false: plain row-major store.
// =====================================================================
template<bool PROJ>
__global__ __launch_bounds__(256)
void mfma_gemm_kernel(const float* __restrict__ Xq, const float* __restrict__ Xk,
                      const float* __restrict__ Xv,
                      const float* __restrict__ Wq, const float* __restrict__ Wk,
                      const float* __restrict__ Wv,
                      float* __restrict__ Oq, float* __restrict__ Ok,
                      float* __restrict__ Ov)
{
    const int z = PROJ ? blockIdx.z : 0;
    const float* X = (!PROJ || z == 0) ? Xq : (z == 1) ? Xk : Xv;
    const float* W = (!PROJ || z == 0) ? Wq : (z == 1) ? Wk : Wv;
    float* O       = (!PROJ || z == 0) ? Oq : (z == 1) ? Ok : Ov;

    __shared__ unsigned short As[128 * LDA];
    __shared__ unsigned short Bs[128 * LDA];

    const int tid  = threadIdx.x;
    const int m0   = blockIdx.y * 128;
    const int n0   = blockIdx.x * 128;
    const int lane = tid & 63;
    const int wid  = tid >> 6;
    const int wm   = (wid >> 1) * 64;
    const int wn   = (wid & 1) * 64;
    const int r16  = lane & 15;
    const int qh   = lane >> 4;

    f32x4 acc[4][4];
#pragma unroll
    for (int i = 0; i < 4; ++i)
#pragma unroll
        for (int j = 0; j < 4; ++j) acc[i][j] = (f32x4)0.0f;

    for (int kt = 0; kt < DMODEL; kt += 32) {
#pragma unroll
        for (int i = 0; i < 4; ++i) {
            int f = tid + i * 256;               // 0..1023
            int row = f >> 3;                    // 0..127
            int c4  = (f & 7) << 2;              // 0,4,...,28
            float4 xv = *(const float4*)(X + (size_t)(m0 + row) * DMODEL + kt + c4);
            ushort4 hx = make_ushort4(f2bf(xv.x), f2bf(xv.y), f2bf(xv.z), f2bf(xv.w));
            *(ushort4*)&As[row * LDA + c4] = hx;
            float4 wv = *(const float4*)(W + (size_t)(n0 + row) * DMODEL + kt + c4);
            ushort4 hw = make_ushort4(f2bf(wv.x), f2bf(wv.y), f2bf(wv.z), f2bf(wv.w));
            *(ushort4*)&Bs[row * LDA + c4] = hw;
        }
        __syncthreads();

        bf16x8 af[4], bg[4];
#pragma unroll
        for (int fm = 0; fm < 4; ++fm)
            af[fm] = *(const bf16x8*)&As[(wm + fm * 16 + r16) * LDA + qh * 8];
#pragma unroll
        for (int fn = 0; fn < 4; ++fn)
            bg[fn] = *(const bf16x8*)&Bs[(wn + fn * 16 + r16) * LDA + qh * 8];
#pragma unroll
        for (int fm = 0; fm < 4; ++fm)
#pragma unroll
            for (int fn = 0; fn < 4; ++fn)
                acc[fm][fn] = __builtin_amdgcn_mfma_f32_16x16x32_bf16(
                    af[fm], bg[fn], acc[fm][fn], 0, 0, 0);
        __syncthreads();
    }

    const float sc = (PROJ && z < 2) ? 0.125f : 1.f;
#pragma unroll
    for (int fm = 0; fm < 4; ++fm) {
#pragma unroll
        for (int r = 0; r < 4; ++r) {
            int m = m0 + wm + fm * 16 + qh * 4 + r;
#pragma unroll
            for (int fn = 0; fn < 4; ++fn) {
                int n = n0 + wn + fn * 16 + r16;
                float y = acc[fm][fn][r];
                if (PROJ) {
                    int b = m >> 10, l = m & 1023;
                    int h = n >> 6, e = n & 63;
                    y *= sc;
                    if (z < 2) y = (y > 0.f) ? y + 1.f : __expf(y);
                    O[(((size_t)(b * H_HEADS + h)) * LSEQ + l) * DHEAD + e] = y;
                } else {
                    O[(size_t)m * DMODEL + n] = y;
                }
            }
        }
    }
}

// =====================================================================
// Per-chunk KV outer-product sums (unchanged from R1).
// =====================================================================
__global__ __launch_bounds__(256)
void chunk_kv_kernel(const float* __restrict__ kp, const float* __restrict__ vp,
                     float* __restrict__ S, float* __restrict__ z, int NC)
{
    const int c = blockIdx.x, bh = blockIdx.y;
    const int tid = threadIdx.x;
    const int txx = tid & 15, tyy = tid >> 4;

    __shared__ float ks[64][64];
    __shared__ float vs[64][64];

    const size_t base = ((size_t)bh * LSEQ + (size_t)c * CHUNK) * DHEAD;
#pragma unroll
    for (int i = 0; i < 4; ++i) {
        int f = tid + i * 256;
        int row = f >> 4, qd = (f & 15) * 4;
        *(float4*)&ks[row][qd] = *(const float4*)(kp + base + row * 64 + qd);
        *(float4*)&vs[row][qd] = *(const float4*)(vp + base + row * 64 + qd);
    }
    __syncthreads();

    float acc[4][4];
#pragma unroll
    for (int i = 0; i < 4; ++i)
#pragma unroll
        for (int j = 0; j < 4; ++j) acc[i][j] = 0.f;

    for (int t = 0; t < 64; ++t) {
        float a[4];
        float4 b4 = *(const float4*)&vs[t][txx * 4];
#pragma unroll
        for (int ii = 0; ii < 4; ++ii) a[ii] = ks[t][tyy * 4 + ii];
#pragma unroll
        for (int ii = 0; ii < 4; ++ii) {
            acc[ii][0] = fmaf(a[ii], b4.x, acc[ii][0]);
            acc[ii][1] = fmaf(a[ii], b4.y, acc[ii][1]);
            acc[ii][2] = fmaf(a[ii], b4.z, acc[ii][2]);
            acc[ii][3] = fmaf(a[ii], b4.w, acc[ii][3]);
        }
    }

    const size_t sbase = ((size_t)bh * NC + c) * (DHEAD * DHEAD);
#pragma unroll
    for (int ii = 0; ii < 4; ++ii) {
        int i = tyy * 4 + ii;
        *(float4*)&S[sbase + (size_t)i * 64 + txx * 4] =
            make_float4(acc[ii][0], acc[ii][1], acc[ii][2], acc[ii][3]);
    }

    if (tid < 64) {
        float s = 0.f;
        for (int t = 0; t < 64; ++t) s += ks[t][tid];
        z[((size_t)bh * NC + c) * 64 + tid] = s;
    }
}

// =====================================================================
// Exclusive prefix over chunks (unchanged from R1).
// =====================================================================
__global__ __launch_bounds__(256)
void prefix_kernel(float* __restrict__ S, float* __restrict__ z, int NC)
{
    const int bh = blockIdx.x;
    const int tid = threadIdx.x;
    for (int e = tid; e < DHEAD * DHEAD; e += 256) {
        float run = 0.f;
        for (int c = 0; c < NC; ++c) {
            size_t idx = ((size_t)bh * NC + c) * (DHEAD * DHEAD) + e;
            float tmp = S[idx];
            S[idx] = run;
            run += tmp;
        }
    }
    if (tid < 64) {
        float run = 0.f;
        for (int c = 0; c < NC; ++c) {
            size_t idx = ((size_t)bh * NC + c) * 64 + tid;
            float tmp = z[idx];
            z[idx] = run;
            run += tmp;
        }
    }
}

// =====================================================================
// Per-chunk causal attention output (unchanged from R1).
// =====================================================================
__global__ __launch_bounds__(256)
void attn_chunk_kernel(const float* __restrict__ qp, const float* __restrict__ kp,
                       const float* __restrict__ vp,
                       const float* __restrict__ Spre, const float* __restrict__ zpre,
                       float* __restrict__ att, int NC)
{
    const int c = blockIdx.x, bh = blockIdx.y;
    const int b = bh >> 4, h = bh & 15;
    const int tid = threadIdx.x;
    const int txx = tid & 15, tyy = tid >> 4;

    __shared__ float qs[64][64];
    __shared__ float ks[64][64];   // Kp, later reused for V
    __shared__ float ss[64][64];   // Sprev
    __shared__ float ps[64][64];   // masked P

    const size_t base = ((size_t)bh * LSEQ + (size_t)c * CHUNK) * DHEAD;
    const size_t sbase = ((size_t)bh * NC + c) * (DHEAD * DHEAD);
    const float* zp = zpre + ((size_t)bh * NC + c) * 64;

#pragma unroll
    for (int i = 0; i < 4; ++i) {
        int f = tid + i * 256;
        int row = f >> 4, qd = (f & 15) * 4;
        *(float4*)&qs[row][qd] = *(const float4*)(qp + base + row * 64 + qd);
        *(float4*)&ks[row][qd] = *(const float4*)(kp + base + row * 64 + qd);
        *(float4*)&ss[row][qd] = *(const float4*)(Spre + sbase + row * 64 + qd);
    }
    __syncthreads();

    float oacc[4][4], pacc[4][4], den[4];
#pragma unroll
    for (int i = 0; i < 4; ++i) {
        den[i] = 0.f;
#pragma unroll
        for (int j = 0; j < 4; ++j) { oacc[i][j] = 0.f; pacc[i][j] = 0.f; }
    }

    for (int k = 0; k < 64; ++k) {
        float a[4], bb[4];
        float4 s4 = *(const float4*)&ss[k][txx * 4];
        float zk = zp[k];
#pragma unroll
        for (int ii = 0; ii < 4; ++ii) a[ii] = qs[tyy * 4 + ii][k];
#pragma unroll
        for (int jj = 0; jj < 4; ++jj) bb[jj] = ks[txx * 4 + jj][k];
#pragma unroll
        for (int ii = 0; ii < 4; ++ii) {
            den[ii] = fmaf(a[ii], zk, den[ii]);
            oacc[ii][0] = fmaf(a[ii], s4.x, oacc[ii][0]);
            oacc[ii][1] = fmaf(a[ii], s4.y, oacc[ii][1]);
            oacc[ii][2] = fmaf(a[ii], s4.z, oacc[ii][2]);
            oacc[ii][3] = fmaf(a[ii], s4.w, oacc[ii][3]);
#pragma unroll
            for (int jj = 0; jj < 4; ++jj)
                pacc[ii][jj] = fmaf(a[ii], bb[jj], pacc[ii][jj]);
        }
    }

#pragma unroll
    for (int ii = 0; ii < 4; ++ii) {
        int t = tyy * 4 + ii;
#pragma unroll
        for (int jj = 0; jj < 4; ++jj) {
            int s = txx * 4 + jj;
            ps[t][s] = (s <= t) ? pacc[ii][jj] : 0.f;
        }
    }
    __syncthreads();

    // reload V into ks
#pragma unroll
    for (int i = 0; i < 4; ++i) {
        int f = tid + i * 256;
        int row = f >> 4, qd = (f & 15) * 4;
        *(float4*)&ks[row][qd] = *(const float4*)(vp + base + row * 64 + qd);
    }
    __syncthreads();

    for (int s = 0; s < 64; ++s) {
        float4 v4 = *(const float4*)&ks[s][txx * 4];
#pragma unroll
        for (int ii = 0; ii < 4; ++ii) {
            float p = ps[tyy * 4 + ii][s];
            den[ii] += p;
            oacc[ii][0] = fmaf(p, v4.x, oacc[ii][0]);
            oacc[ii][1] = fmaf(p, v4.y, oacc[ii][1]);
            oacc[ii][2] = fmaf(p, v4.z, oacc[ii][2]);
            oacc[ii][3] = fmaf(p, v4.w, oacc[ii][3]);
        }
    }

#pragma unroll
    for (int ii = 0; ii < 4; ++ii) {
        int t = tyy * 4 + ii;
        int l = c * CHUNK + t;
        float inv = 1.f / (den[ii] + EPS_F);
#pragma unroll
        for (int jj = 0; jj < 4; ++jj) {
            int e = txx * 4 + jj;
            att[((size_t)b * LSEQ + l) * DMODEL + h * DHEAD + e] = oacc[ii][jj] * inv;
        }
    }
}

// =====================================================================
extern "C" void kernel_launch(void* const* d_in, const int* in_sizes, int n_in,
                              void* d_out, int out_size, void* d_ws, size_t ws_size,
                              hipStream_t stream)
{
    const float* query = (const float*)d_in[0];
    const float* key_  = (const float*)d_in[1];
    const float* value = (const float*)d_in[2];
    const float* Wq = (const float*)d_in[3];
    const float* Wk = (const float*)d_in[4];
    const float* Wv = (const float*)d_in[5];
    const float* Wo = (const float*)d_in[6];
    float* out = (float*)d_out;

    const int B  = in_sizes[0] / (LSEQ * DMODEL);   // 2
    const int M  = B * LSEQ;                        // 2048
    const int BH = B * H_HEADS;                     // 32
    const int NC = LSEQ / CHUNK;                    // 16

    float* ws  = (float*)d_ws;
    float* qp  = ws;
    float* kp  = qp  + (size_t)BH * LSEQ * DHEAD;
    float* vp  = kp  + (size_t)BH * LSEQ * DHEAD;
    float* att = vp  + (size_t)BH * LSEQ * DHEAD;
    float* S   = att + (size_t)M * DMODEL;
    float* z   = S   + (size_t)BH * NC * DHEAD * DHEAD;

    dim3 blk(256);
    mfma_gemm_kernel<true><<<dim3(DMODEL / 128, M / 128, 3), blk, 0, stream>>>(
        query, key_, value, Wq, Wk, Wv, qp, kp, vp);
    chunk_kv_kernel<<<dim3(NC, BH), blk, 0, stream>>>(kp, vp, S, z, NC);
    prefix_kernel<<<dim3(BH), blk, 0, stream>>>(S, z, NC);
    attn_chunk_kernel<<<dim3(NC, BH), blk, 0, stream>>>(qp, kp, vp, S, z, att, NC);
    mfma_gemm_kernel<false><<<dim3(DMODEL / 128, M / 128, 1), blk, 0, stream>>>(
        att, nullptr, nullptr, Wo, nullptr, nullptr, out, nullptr, nullptr);
}

// Round 3
// 131.937 us; speedup vs baseline: 4.2108x; 1.4730x over previous
//
#include <hip/hip_runtime.h>
#include <hip/hip_bf16.h>
#include <math.h>

#define H_HEADS 16
#define DMODEL  1024
#define DHEAD   64
#define LSEQ    1024
#define CHUNK   64
#define NCHUNK  16
#define EPS_F   1e-6f

typedef __attribute__((ext_vector_type(8))) short bf16x8;   // 8 bf16 = 4 VGPRs
typedef __attribute__((ext_vector_type(4))) float f32x4;    // MFMA 16x16 accumulator

__device__ inline unsigned short f2bf(float f) {
    unsigned int u = __float_as_uint(f);
    u += 0x7FFF + ((u >> 16) & 1);          // round-to-nearest-even
    return (unsigned short)(u >> 16);
}

#define LDA 40   // LDS row stride in bf16 elems (80B = 16B-aligned, conflict-reduced)

// =====================================================================
// bf16 MFMA GEMM: C = X @ W^T.  X:[M,K] fp32 row-major, W:[N,K] fp32 row-major.
// 128x128 tile, BK=32, 256 thr = 4 waves (2x2 of 64x64), 16x16x32 MFMA.
// =====================================================================
template<bool PROJ>
__global__ __launch_bounds__(256)
void mfma_gemm_kernel(const float* __restrict__ Xq, const float* __restrict__ Xk,
                      const float* __restrict__ Xv,
                      const float* __restrict__ Wq, const float* __restrict__ Wk,
                      const float* __restrict__ Wv,
                      float* __restrict__ Oq, float* __restrict__ Ok,
                      float* __restrict__ Ov)
{
    const int z = PROJ ? blockIdx.z : 0;
    const float* X = (!PROJ || z == 0) ? Xq : (z == 1) ? Xk : Xv;
    const float* W = (!PROJ || z == 0) ? Wq : (z == 1) ? Wk : Wv;
    float* O       = (!PROJ || z == 0) ? Oq : (z == 1) ? Ok : Ov;

    __shared__ unsigned short As[128 * LDA];
    __shared__ unsigned short Bs[128 * LDA];

    const int tid  = threadIdx.x;
    const int m0   = blockIdx.y * 128;
    const int n0   = blockIdx.x * 128;
    const int lane = tid & 63;
    const int wid  = tid >> 6;
    const int wm   = (wid >> 1) * 64;
    const int wn   = (wid & 1) * 64;
    const int r16  = lane & 15;
    const int qh   = lane >> 4;

    f32x4 acc[4][4];
#pragma unroll
    for (int i = 0; i < 4; ++i)
#pragma unroll
        for (int j = 0; j < 4; ++j) acc[i][j] = (f32x4)0.0f;

    for (int kt = 0; kt < DMODEL; kt += 32) {
#pragma unroll
        for (int i = 0; i < 4; ++i) {
            int f = tid + i * 256;               // 0..1023
            int row = f >> 3;                    // 0..127
            int c4  = (f & 7) << 2;              // 0,4,...,28
            float4 xv = *(const float4*)(X + (size_t)(m0 + row) * DMODEL + kt + c4);
            ushort4 hx = make_ushort4(f2bf(xv.x), f2bf(xv.y), f2bf(xv.z), f2bf(xv.w));
            *(ushort4*)&As[row * LDA + c4] = hx;
            float4 wv = *(const float4*)(W + (size_t)(n0 + row) * DMODEL + kt + c4);
            ushort4 hw = make_ushort4(f2bf(wv.x), f2bf(wv.y), f2bf(wv.z), f2bf(wv.w));
            *(ushort4*)&Bs[row * LDA + c4] = hw;
        }
        __syncthreads();

        bf16x8 af[4], bg[4];
#pragma unroll
        for (int fm = 0; fm < 4; ++fm)
            af[fm] = *(const bf16x8*)&As[(wm + fm * 16 + r16) * LDA + qh * 8];
#pragma unroll
        for (int fn = 0; fn < 4; ++fn)
            bg[fn] = *(const bf16x8*)&Bs[(wn + fn * 16 + r16) * LDA + qh * 8];
#pragma unroll
        for (int fm = 0; fm < 4; ++fm)
#pragma unroll
            for (int fn = 0; fn < 4; ++fn)
                acc[fm][fn] = __builtin_amdgcn_mfma_f32_16x16x32_bf16(
                    af[fm], bg[fn], acc[fm][fn], 0, 0, 0);
        __syncthreads();
    }

    const float sc = (PROJ && z < 2) ? 0.125f : 1.f;
#pragma unroll
    for (int fm = 0; fm < 4; ++fm) {
#pragma unroll
        for (int r = 0; r < 4; ++r) {
            int m = m0 + wm + fm * 16 + qh * 4 + r;
#pragma unroll
            for (int fn = 0; fn < 4; ++fn) {
                int n = n0 + wn + fn * 16 + r16;
                float y = acc[fm][fn][r];
                if (PROJ) {
                    int b = m >> 10, l = m & 1023;
                    int h = n >> 6, e = n & 63;
                    y *= sc;
                    if (z < 2) y = (y > 0.f) ? y + 1.f : __expf(y);
                    O[(((size_t)(b * H_HEADS + h)) * LSEQ + l) * DHEAD + e] = y;
                } else {
                    O[(size_t)m * DMODEL + n] = y;
                }
            }
        }
    }
}

// =====================================================================
// Per-chunk KV outer-product sums (unchanged).
// =====================================================================
__global__ __launch_bounds__(256)
void chunk_kv_kernel(const float* __restrict__ kp, const float* __restrict__ vp,
                     float* __restrict__ S, float* __restrict__ z, int NC)
{
    const int c = blockIdx.x, bh = blockIdx.y;
    const int tid = threadIdx.x;
    const int txx = tid & 15, tyy = tid >> 4;

    __shared__ float ks[64][64];
    __shared__ float vs[64][64];

    const size_t base = ((size_t)bh * LSEQ + (size_t)c * CHUNK) * DHEAD;
#pragma unroll
    for (int i = 0; i < 4; ++i) {
        int f = tid + i * 256;
        int row = f >> 4, qd = (f & 15) * 4;
        *(float4*)&ks[row][qd] = *(const float4*)(kp + base + row * 64 + qd);
        *(float4*)&vs[row][qd] = *(const float4*)(vp + base + row * 64 + qd);
    }
    __syncthreads();

    float acc[4][4];
#pragma unroll
    for (int i = 0; i < 4; ++i)
#pragma unroll
        for (int j = 0; j < 4; ++j) acc[i][j] = 0.f;

    for (int t = 0; t < 64; ++t) {
        float a[4];
        float4 b4 = *(const float4*)&vs[t][txx * 4];
#pragma unroll
        for (int ii = 0; ii < 4; ++ii) a[ii] = ks[t][tyy * 4 + ii];
#pragma unroll
        for (int ii = 0; ii < 4; ++ii) {
            acc[ii][0] = fmaf(a[ii], b4.x, acc[ii][0]);
            acc[ii][1] = fmaf(a[ii], b4.y, acc[ii][1]);
            acc[ii][2] = fmaf(a[ii], b4.z, acc[ii][2]);
            acc[ii][3] = fmaf(a[ii], b4.w, acc[ii][3]);
        }
    }

    const size_t sbase = ((size_t)bh * NC + c) * (DHEAD * DHEAD);
#pragma unroll
    for (int ii = 0; ii < 4; ++ii) {
        int i = tyy * 4 + ii;
        *(float4*)&S[sbase + (size_t)i * 64 + txx * 4] =
            make_float4(acc[ii][0], acc[ii][1], acc[ii][2], acc[ii][3]);
    }

    if (tid < 64) {
        float s = 0.f;
        for (int t = 0; t < 64; ++t) s += ks[t][tid];
        z[((size_t)bh * NC + c) * 64 + tid] = s;
    }
}

// =====================================================================
// Exclusive prefix over chunks — PARALLEL version.
// grid = BH*16 blocks x 256 thr: thread owns one element e of S for one bh.
// All 16 chunk loads issued independently (pipelined), scan in registers.
// =====================================================================
__global__ __launch_bounds__(256)
void prefix_kernel(float* __restrict__ S, float* __restrict__ z, int NC)
{
    const int bh   = blockIdx.x >> 4;
    const int eblk = blockIdx.x & 15;
    const int e    = eblk * 256 + threadIdx.x;

    const size_t base = (size_t)bh * NCHUNK * (DHEAD * DHEAD) + e;
    float v[NCHUNK];
#pragma unroll
    for (int c = 0; c < NCHUNK; ++c)
        v[c] = S[base + (size_t)c * (DHEAD * DHEAD)];
    float run = 0.f;
#pragma unroll
    for (int c = 0; c < NCHUNK; ++c) {
        S[base + (size_t)c * (DHEAD * DHEAD)] = run;
        run += v[c];
    }

    if (eblk == 0 && threadIdx.x < DHEAD) {
        const size_t zb = (size_t)bh * NCHUNK * DHEAD + threadIdx.x;
        float zv[NCHUNK];
#pragma unroll
        for (int c = 0; c < NCHUNK; ++c)
            zv[c] = z[zb + (size_t)c * DHEAD];
        float zr = 0.f;
#pragma unroll
        for (int c = 0; c < NCHUNK; ++c) {
            z[zb + (size_t)c * DHEAD] = zr;
            zr += zv[c];
        }
    }
}

// =====================================================================
// Per-chunk causal attention output (unchanged).
// =====================================================================
__global__ __launch_bounds__(256)
void attn_chunk_kernel(const float* __restrict__ qp, const float* __restrict__ kp,
                       const float* __restrict__ vp,
                       const float* __restrict__ Spre, const float* __restrict__ zpre,
                       float* __restrict__ att, int NC)
{
    const int c = blockIdx.x, bh = blockIdx.y;
    const int b = bh >> 4, h = bh & 15;
    const int tid = threadIdx.x;
    const int txx = tid & 15, tyy = tid >> 4;

    __shared__ float qs[64][64];
    __shared__ float ks[64][64];   // Kp, later reused for V
    __shared__ float ss[64][64];   // Sprev
    __shared__ float ps[64][64];   // masked P

    const size_t base = ((size_t)bh * LSEQ + (size_t)c * CHUNK) * DHEAD;
    const size_t sbase = ((size_t)bh * NC + c) * (DHEAD * DHEAD);
    const float* zp = zpre + ((size_t)bh * NC + c) * 64;

#pragma unroll
    for (int i = 0; i < 4; ++i) {
        int f = tid + i * 256;
        int row = f >> 4, qd = (f & 15) * 4;
        *(float4*)&qs[row][qd] = *(const float4*)(qp + base + row * 64 + qd);
        *(float4*)&ks[row][qd] = *(const float4*)(kp + base + row * 64 + qd);
        *(float4*)&ss[row][qd] = *(const float4*)(Spre + sbase + row * 64 + qd);
    }
    __syncthreads();

    float oacc[4][4], pacc[4][4], den[4];
#pragma unroll
    for (int i = 0; i < 4; ++i) {
        den[i] = 0.f;
#pragma unroll
        for (int j = 0; j < 4; ++j) { oacc[i][j] = 0.f; pacc[i][j] = 0.f; }
    }

    for (int k = 0; k < 64; ++k) {
        float a[4], bb[4];
        float4 s4 = *(const float4*)&ss[k][txx * 4];
        float zk = zp[k];
#pragma unroll
        for (int ii = 0; ii < 4; ++ii) a[ii] = qs[tyy * 4 + ii][k];
#pragma unroll
        for (int jj = 0; jj < 4; ++jj) bb[jj] = ks[txx * 4 + jj][k];
#pragma unroll
        for (int ii = 0; ii < 4; ++ii) {
            den[ii] = fmaf(a[ii], zk, den[ii]);
            oacc[ii][0] = fmaf(a[ii], s4.x, oacc[ii][0]);
            oacc[ii][1] = fmaf(a[ii], s4.y, oacc[ii][1]);
            oacc[ii][2] = fmaf(a[ii], s4.z, oacc[ii][2]);
            oacc[ii][3] = fmaf(a[ii], s4.w, oacc[ii][3]);
#pragma unroll
            for (int jj = 0; jj < 4; ++jj)
                pacc[ii][jj] = fmaf(a[ii], bb[jj], pacc[ii][jj]);
        }
    }

#pragma unroll
    for (int ii = 0; ii < 4; ++ii) {
        int t = tyy * 4 + ii;
#pragma unroll
        for (int jj = 0; jj < 4; ++jj) {
            int s = txx * 4 + jj;
            ps[t][s] = (s <= t) ? pacc[ii][jj] : 0.f;
        }
    }
    __syncthreads();

    // reload V into ks
#pragma unroll
    for (int i = 0; i < 4; ++i) {
        int f = tid + i * 256;
        int row = f >> 4, qd = (f & 15) * 4;
        *(float4*)&ks[row][qd] = *(const float4*)(vp + base + row * 64 + qd);
    }
    __syncthreads();

    for (int s = 0; s < 64; ++s) {
        float4 v4 = *(const float4*)&ks[s][txx * 4];
#pragma unroll
        for (int ii = 0; ii < 4; ++ii) {
            float p = ps[tyy * 4 + ii][s];
            den[ii] += p;
            oacc[ii][0] = fmaf(p, v4.x, oacc[ii][0]);
            oacc[ii][1] = fmaf(p, v4.y, oacc[ii][1]);
            oacc[ii][2] = fmaf(p, v4.z, oacc[ii][2]);
            oacc[ii][3] = fmaf(p, v4.w, oacc[ii][3]);
        }
    }

#pragma unroll
    for (int ii = 0; ii < 4; ++ii) {
        int t = tyy * 4 + ii;
        int l = c * CHUNK + t;
        float inv = 1.f / (den[ii] + EPS_F);
#pragma unroll
        for (int jj = 0; jj < 4; ++jj) {
            int e = txx * 4 + jj;
            att[((size_t)b * LSEQ + l) * DMODEL + h * DHEAD + e] = oacc[ii][jj] * inv;
        }
    }
}

// =====================================================================
extern "C" void kernel_launch(void* const* d_in, const int* in_sizes, int n_in,
                              void* d_out, int out_size, void* d_ws, size_t ws_size,
                              hipStream_t stream)
{
    const float* query = (const float*)d_in[0];
    const float* key_  = (const float*)d_in[1];
    const float* value = (const float*)d_in[2];
    const float* Wq = (const float*)d_in[3];
    const float* Wk = (const float*)d_in[4];
    const float* Wv = (const float*)d_in[5];
    const float* Wo = (const float*)d_in[6];
    float* out = (float*)d_out;

    const int B  = in_sizes[0] / (LSEQ * DMODEL);   // 2
    const int M  = B * LSEQ;                        // 2048
    const int BH = B * H_HEADS;                     // 32
    const int NC = LSEQ / CHUNK;                    // 16

    float* ws  = (float*)d_ws;
    float* qp  = ws;
    float* kp  = qp  + (size_t)BH * LSEQ * DHEAD;
    float* vp  = kp  + (size_t)BH * LSEQ * DHEAD;
    float* att = vp  + (size_t)BH * LSEQ * DHEAD;
    float* S   = att + (size_t)M * DMODEL;
    float* z   = S   + (size_t)BH * NC * DHEAD * DHEAD;

    dim3 blk(256);
    mfma_gemm_kernel<true><<<dim3(DMODEL / 128, M / 128, 3), blk, 0, stream>>>(
        query, key_, value, Wq, Wk, Wv, qp, kp, vp);
    chunk_kv_kernel<<<dim3(NC, BH), blk, 0, stream>>>(kp, vp, S, z, NC);
    prefix_kernel<<<dim3(BH * 16), blk, 0, stream>>>(S, z, NC);
    attn_chunk_kernel<<<dim3(NC, BH), blk, 0, stream>>>(qp, kp, vp, S, z, att, NC);
    mfma_gemm_kernel<false><<<dim3(DMODEL / 128, M / 128, 1), blk, 0, stream>>>(
        att, nullptr, nullptr, Wo, nullptr, nullptr, out, nullptr, nullptr);
}

// Round 4
// 105.127 us; speedup vs baseline: 5.2846x; 1.2550x over previous
//
#include <hip/hip_runtime.h>
#include <hip/hip_bf16.h>
#include <math.h>

#define H_HEADS 16
#define DMODEL  1024
#define DHEAD   64
#define LSEQ    1024
#define CHUNK   64
#define NCHUNK  16
#define EPS_F   1e-6f

typedef __attribute__((ext_vector_type(8))) short bf16x8;   // 8 bf16 = 4 VGPRs
typedef __attribute__((ext_vector_type(4))) float f32x4;    // MFMA 16x16 accumulator

__device__ inline unsigned short f2bf(float f) {
    unsigned int u = __float_as_uint(f);
    u += 0x7FFF + ((u >> 16) & 1);          // round-to-nearest-even
    return (unsigned short)(u >> 16);
}

#define LDA 40   // LDS row stride in bf16 elems (80B: 16B-aligned; 8 words/bank/phase = b128 floor)

// =====================================================================
// fp32 -> bf16 convert: q,k,v -> Xb[3][2M]; Wq,Wk,Wv,Wo -> Wb[4][1M].
// grid = (2048, 7); each block converts 1024 elems (256 thr x float4).
// =====================================================================
__global__ __launch_bounds__(256)
void convert_kernel(const float* __restrict__ q, const float* __restrict__ k,
                    const float* __restrict__ v,
                    const float* __restrict__ Wq, const float* __restrict__ Wk,
                    const float* __restrict__ Wv, const float* __restrict__ Wo,
                    unsigned short* __restrict__ Xb, unsigned short* __restrict__ Wb)
{
    const int y = blockIdx.y;
    const float* src;
    unsigned short* dst;
    int n;
    if (y < 3) {
        src = (y == 0) ? q : (y == 1) ? k : v;
        dst = Xb + (size_t)y * (2 * LSEQ * DMODEL);
        n = 2 * LSEQ * DMODEL;
    } else {
        int w = y - 3;
        src = (w == 0) ? Wq : (w == 1) ? Wk : (w == 2) ? Wv : Wo;
        dst = Wb + (size_t)w * (DMODEL * DMODEL);
        n = DMODEL * DMODEL;
    }
    int idx = (blockIdx.x * 256 + threadIdx.x) * 4;
    if (idx < n) {
        float4 f = *(const float4*)(src + idx);
        ushort4 h = make_ushort4(f2bf(f.x), f2bf(f.y), f2bf(f.z), f2bf(f.w));
        *(ushort4*)(dst + idx) = h;
    }
}

// =====================================================================
// bf16 MFMA projection GEMM: O = phi(X @ W^T * sc) in [B,H,L,d].
// BM=64, BN=128, BK=32, 256 thr = 4 waves (2x2 of 32x64). grid=(8,32,3).
// =====================================================================
__global__ __launch_bounds__(256)
void proj_bf16_kernel(const unsigned short* __restrict__ Xb,
                      const unsigned short* __restrict__ Wb,
                      float* __restrict__ qp, float* __restrict__ kp,
                      float* __restrict__ vp)
{
    const int z = blockIdx.z;
    const unsigned short* X = Xb + (size_t)z * (2 * LSEQ * DMODEL);
    const unsigned short* W = Wb + (size_t)z * (DMODEL * DMODEL);
    float* O = (z == 0) ? qp : (z == 1) ? kp : vp;

    __shared__ unsigned short As[64 * LDA];
    __shared__ unsigned short Bs[128 * LDA];

    const int tid  = threadIdx.x;
    const int m0   = blockIdx.y * 64;
    const int n0   = blockIdx.x * 128;
    const int lane = tid & 63;
    const int wid  = tid >> 6;
    const int wm   = (wid >> 1) * 32;
    const int wn   = (wid & 1) * 64;
    const int r16  = lane & 15;
    const int qh   = lane >> 4;

    const int srow = tid >> 2;        // 0..63
    const int scg  = (tid & 3) * 8;   // bf16 col offset 0,8,16,24

    f32x4 acc[2][4];
#pragma unroll
    for (int i = 0; i < 2; ++i)
#pragma unroll
        for (int j = 0; j < 4; ++j) acc[i][j] = (f32x4)0.0f;

    for (int kt = 0; kt < DMODEL; kt += 32) {
        *(bf16x8*)&As[srow * LDA + scg] =
            *(const bf16x8*)(X + (size_t)(m0 + srow) * DMODEL + kt + scg);
        *(bf16x8*)&Bs[srow * LDA + scg] =
            *(const bf16x8*)(W + (size_t)(n0 + srow) * DMODEL + kt + scg);
        *(bf16x8*)&Bs[(64 + srow) * LDA + scg] =
            *(const bf16x8*)(W + (size_t)(n0 + 64 + srow) * DMODEL + kt + scg);
        __syncthreads();

        bf16x8 af[2], bg[4];
#pragma unroll
        for (int fm = 0; fm < 2; ++fm)
            af[fm] = *(const bf16x8*)&As[(wm + fm * 16 + r16) * LDA + qh * 8];
#pragma unroll
        for (int fn = 0; fn < 4; ++fn)
            bg[fn] = *(const bf16x8*)&Bs[(wn + fn * 16 + r16) * LDA + qh * 8];
#pragma unroll
        for (int fm = 0; fm < 2; ++fm)
#pragma unroll
            for (int fn = 0; fn < 4; ++fn)
                acc[fm][fn] = __builtin_amdgcn_mfma_f32_16x16x32_bf16(
                    af[fm], bg[fn], acc[fm][fn], 0, 0, 0);
        __syncthreads();
    }

    const float sc = (z < 2) ? 0.125f : 1.f;
#pragma unroll
    for (int fm = 0; fm < 2; ++fm) {
#pragma unroll
        for (int r = 0; r < 4; ++r) {
            int m = m0 + wm + fm * 16 + qh * 4 + r;
            int b = m >> 10, l = m & 1023;
#pragma unroll
            for (int fn = 0; fn < 4; ++fn) {
                int n = n0 + wn + fn * 16 + r16;
                int h = n >> 6, e = n & 63;
                float y = acc[fm][fn][r] * sc;
                if (z < 2) y = (y > 0.f) ? y + 1.f : __expf(y);
                O[(((size_t)(b * H_HEADS + h)) * LSEQ + l) * DHEAD + e] = y;
            }
        }
    }
}

// =====================================================================
// bf16 MFMA output GEMM: out = attb @ Wo^T (fp32 out, row-major).
// BM=64, BN=128, BK=32. grid=(8,32).
// =====================================================================
__global__ __launch_bounds__(256)
void gemm_out_bf16_kernel(const unsigned short* __restrict__ A,
                          const unsigned short* __restrict__ W,
                          float* __restrict__ out)
{
    __shared__ unsigned short As[64 * LDA];
    __shared__ unsigned short Bs[128 * LDA];

    const int tid  = threadIdx.x;
    const int m0   = blockIdx.y * 64;
    const int n0   = blockIdx.x * 128;
    const int lane = tid & 63;
    const int wid  = tid >> 6;
    const int wm   = (wid >> 1) * 32;
    const int wn   = (wid & 1) * 64;
    const int r16  = lane & 15;
    const int qh   = lane >> 4;

    const int srow = tid >> 2;
    const int scg  = (tid & 3) * 8;

    f32x4 acc[2][4];
#pragma unroll
    for (int i = 0; i < 2; ++i)
#pragma unroll
        for (int j = 0; j < 4; ++j) acc[i][j] = (f32x4)0.0f;

    for (int kt = 0; kt < DMODEL; kt += 32) {
        *(bf16x8*)&As[srow * LDA + scg] =
            *(const bf16x8*)(A + (size_t)(m0 + srow) * DMODEL + kt + scg);
        *(bf16x8*)&Bs[srow * LDA + scg] =
            *(const bf16x8*)(W + (size_t)(n0 + srow) * DMODEL + kt + scg);
        *(bf16x8*)&Bs[(64 + srow) * LDA + scg] =
            *(const bf16x8*)(W + (size_t)(n0 + 64 + srow) * DMODEL + kt + scg);
        __syncthreads();

        bf16x8 af[2], bg[4];
#pragma unroll
        for (int fm = 0; fm < 2; ++fm)
            af[fm] = *(const bf16x8*)&As[(wm + fm * 16 + r16) * LDA + qh * 8];
#pragma unroll
        for (int fn = 0; fn < 4; ++fn)
            bg[fn] = *(const bf16x8*)&Bs[(wn + fn * 16 + r16) * LDA + qh * 8];
#pragma unroll
        for (int fm = 0; fm < 2; ++fm)
#pragma unroll
            for (int fn = 0; fn < 4; ++fn)
                acc[fm][fn] = __builtin_amdgcn_mfma_f32_16x16x32_bf16(
                    af[fm], bg[fn], acc[fm][fn], 0, 0, 0);
        __syncthreads();
    }

#pragma unroll
    for (int fm = 0; fm < 2; ++fm) {
#pragma unroll
        for (int r = 0; r < 4; ++r) {
            int m = m0 + wm + fm * 16 + qh * 4 + r;
#pragma unroll
            for (int fn = 0; fn < 4; ++fn) {
                int n = n0 + wn + fn * 16 + r16;
                out[(size_t)m * DMODEL + n] = acc[fm][fn][r];
            }
        }
    }
}

// =====================================================================
// Per-chunk KV outer-product sums (unchanged).
// =====================================================================
__global__ __launch_bounds__(256)
void chunk_kv_kernel(const float* __restrict__ kp, const float* __restrict__ vp,
                     float* __restrict__ S, float* __restrict__ z, int NC)
{
    const int c = blockIdx.x, bh = blockIdx.y;
    const int tid = threadIdx.x;
    const int txx = tid & 15, tyy = tid >> 4;

    __shared__ float ks[64][64];
    __shared__ float vs[64][64];

    const size_t base = ((size_t)bh * LSEQ + (size_t)c * CHUNK) * DHEAD;
#pragma unroll
    for (int i = 0; i < 4; ++i) {
        int f = tid + i * 256;
        int row = f >> 4, qd = (f & 15) * 4;
        *(float4*)&ks[row][qd] = *(const float4*)(kp + base + row * 64 + qd);
        *(float4*)&vs[row][qd] = *(const float4*)(vp + base + row * 64 + qd);
    }
    __syncthreads();

    float acc[4][4];
#pragma unroll
    for (int i = 0; i < 4; ++i)
#pragma unroll
        for (int j = 0; j < 4; ++j) acc[i][j] = 0.f;

    for (int t = 0; t < 64; ++t) {
        float a[4];
        float4 b4 = *(const float4*)&vs[t][txx * 4];
#pragma unroll
        for (int ii = 0; ii < 4; ++ii) a[ii] = ks[t][tyy * 4 + ii];
#pragma unroll
        for (int ii = 0; ii < 4; ++ii) {
            acc[ii][0] = fmaf(a[ii], b4.x, acc[ii][0]);
            acc[ii][1] = fmaf(a[ii], b4.y, acc[ii][1]);
            acc[ii][2] = fmaf(a[ii], b4.z, acc[ii][2]);
            acc[ii][3] = fmaf(a[ii], b4.w, acc[ii][3]);
        }
    }

    const size_t sbase = ((size_t)bh * NC + c) * (DHEAD * DHEAD);
#pragma unroll
    for (int ii = 0; ii < 4; ++ii) {
        int i = tyy * 4 + ii;
        *(float4*)&S[sbase + (size_t)i * 64 + txx * 4] =
            make_float4(acc[ii][0], acc[ii][1], acc[ii][2], acc[ii][3]);
    }

    if (tid < 64) {
        float s = 0.f;
        for (int t = 0; t < 64; ++t) s += ks[t][tid];
        z[((size_t)bh * NC + c) * 64 + tid] = s;
    }
}

// =====================================================================
// Exclusive prefix over chunks — parallel (unchanged from R3).
// =====================================================================
__global__ __launch_bounds__(256)
void prefix_kernel(float* __restrict__ S, float* __restrict__ z, int NC)
{
    const int bh   = blockIdx.x >> 4;
    const int eblk = blockIdx.x & 15;
    const int e    = eblk * 256 + threadIdx.x;

    const size_t base = (size_t)bh * NCHUNK * (DHEAD * DHEAD) + e;
    float v[NCHUNK];
#pragma unroll
    for (int c = 0; c < NCHUNK; ++c)
        v[c] = S[base + (size_t)c * (DHEAD * DHEAD)];
    float run = 0.f;
#pragma unroll
    for (int c = 0; c < NCHUNK; ++c) {
        S[base + (size_t)c * (DHEAD * DHEAD)] = run;
        run += v[c];
    }

    if (eblk == 0 && threadIdx.x < DHEAD) {
        const size_t zb = (size_t)bh * NCHUNK * DHEAD + threadIdx.x;
        float zv[NCHUNK];
#pragma unroll
        for (int c = 0; c < NCHUNK; ++c)
            zv[c] = z[zb + (size_t)c * DHEAD];
        float zr = 0.f;
#pragma unroll
        for (int c = 0; c < NCHUNK; ++c) {
            z[zb + (size_t)c * DHEAD] = zr;
            zr += zv[c];
        }
    }
}

// =====================================================================
// Per-chunk causal attention output; att stored as bf16.
// =====================================================================
__global__ __launch_bounds__(256)
void attn_chunk_kernel(const float* __restrict__ qp, const float* __restrict__ kp,
                       const float* __restrict__ vp,
                       const float* __restrict__ Spre, const float* __restrict__ zpre,
                       unsigned short* __restrict__ att, int NC)
{
    const int c = blockIdx.x, bh = blockIdx.y;
    const int b = bh >> 4, h = bh & 15;
    const int tid = threadIdx.x;
    const int txx = tid & 15, tyy = tid >> 4;

    __shared__ float qs[64][64];
    __shared__ float ks[64][64];   // Kp, later reused for V
    __shared__ float ss[64][64];   // Sprev
    __shared__ float ps[64][64];   // masked P

    const size_t base = ((size_t)bh * LSEQ + (size_t)c * CHUNK) * DHEAD;
    const size_t sbase = ((size_t)bh * NC + c) * (DHEAD * DHEAD);
    const float* zp = zpre + ((size_t)bh * NC + c) * 64;

#pragma unroll
    for (int i = 0; i < 4; ++i) {
        int f = tid + i * 256;
        int row = f >> 4, qd = (f & 15) * 4;
        *(float4*)&qs[row][qd] = *(const float4*)(qp + base + row * 64 + qd);
        *(float4*)&ks[row][qd] = *(const float4*)(kp + base + row * 64 + qd);
        *(float4*)&ss[row][qd] = *(const float4*)(Spre + sbase + row * 64 + qd);
    }
    __syncthreads();

    float oacc[4][4], pacc[4][4], den[4];
#pragma unroll
    for (int i = 0; i < 4; ++i) {
        den[i] = 0.f;
#pragma unroll
        for (int j = 0; j < 4; ++j) { oacc[i][j] = 0.f; pacc[i][j] = 0.f; }
    }

    for (int k = 0; k < 64; ++k) {
        float a[4], bb[4];
        float4 s4 = *(const float4*)&ss[k][txx * 4];
        float zk = zp[k];
#pragma unroll
        for (int ii = 0; ii < 4; ++ii) a[ii] = qs[tyy * 4 + ii][k];
#pragma unroll
        for (int jj = 0; jj < 4; ++jj) bb[jj] = ks[txx * 4 + jj][k];
#pragma unroll
        for (int ii = 0; ii < 4; ++ii) {
            den[ii] = fmaf(a[ii], zk, den[ii]);
            oacc[ii][0] = fmaf(a[ii], s4.x, oacc[ii][0]);
            oacc[ii][1] = fmaf(a[ii], s4.y, oacc[ii][1]);
            oacc[ii][2] = fmaf(a[ii], s4.z, oacc[ii][2]);
            oacc[ii][3] = fmaf(a[ii], s4.w, oacc[ii][3]);
#pragma unroll
            for (int jj = 0; jj < 4; ++jj)
                pacc[ii][jj] = fmaf(a[ii], bb[jj], pacc[ii][jj]);
        }
    }

#pragma unroll
    for (int ii = 0; ii < 4; ++ii) {
        int t = tyy * 4 + ii;
#pragma unroll
        for (int jj = 0; jj < 4; ++jj) {
            int s = txx * 4 + jj;
            ps[t][s] = (s <= t) ? pacc[ii][jj] : 0.f;
        }
    }
    __syncthreads();

    // reload V into ks
#pragma unroll
    for (int i = 0; i < 4; ++i) {
        int f = tid + i * 256;
        int row = f >> 4, qd = (f & 15) * 4;
        *(float4*)&ks[row][qd] = *(const float4*)(vp + base + row * 64 + qd);
    }
    __syncthreads();

    for (int s = 0; s < 64; ++s) {
        float4 v4 = *(const float4*)&ks[s][txx * 4];
#pragma unroll
        for (int ii = 0; ii < 4; ++ii) {
            float p = ps[tyy * 4 + ii][s];
            den[ii] += p;
            oacc[ii][0] = fmaf(p, v4.x, oacc[ii][0]);
            oacc[ii][1] = fmaf(p, v4.y, oacc[ii][1]);
            oacc[ii][2] = fmaf(p, v4.z, oacc[ii][2]);
            oacc[ii][3] = fmaf(p, v4.w, oacc[ii][3]);
        }
    }

#pragma unroll
    for (int ii = 0; ii < 4; ++ii) {
        int t = tyy * 4 + ii;
        int l = c * CHUNK + t;
        float inv = 1.f / (den[ii] + EPS_F);
#pragma unroll
        for (int jj = 0; jj < 4; ++jj) {
            int e = txx * 4 + jj;
            att[((size_t)b * LSEQ + l) * DMODEL + h * DHEAD + e] =
                f2bf(oacc[ii][jj] * inv);
        }
    }
}

// =====================================================================
extern "C" void kernel_launch(void* const* d_in, const int* in_sizes, int n_in,
                              void* d_out, int out_size, void* d_ws, size_t ws_size,
                              hipStream_t stream)
{
    const float* query = (const float*)d_in[0];
    const float* key_  = (const float*)d_in[1];
    const float* value = (const float*)d_in[2];
    const float* Wq = (const float*)d_in[3];
    const float* Wk = (const float*)d_in[4];
    const float* Wv = (const float*)d_in[5];
    const float* Wo = (const float*)d_in[6];
    float* out = (float*)d_out;

    const int M  = 2 * LSEQ;     // 2048
    const int BH = 2 * H_HEADS;  // 32
    const int NC = NCHUNK;       // 16

    // ws layout (bytes):
    //   [0, 8.4M)      Wb   : bf16 Wq|Wk|Wv|Wo          4 x 1M x 2B
    //   [8.4M, 33.6M)  qp,kp,vp : fp32 [B,H,L,d]        3 x 2M x 4B
    //   [33.6M, 37.7M) attb : bf16 [M,1024]             2M x 2B
    //   [37.7M, 50.3M) Xb   : bf16 q|k|v (dead after proj)
    //   [37.7M, 46.3M) S,z  : fp32 (alias Xb; written after proj)
    char* wsb = (char*)d_ws;
    unsigned short* Wb   = (unsigned short*)(wsb);
    float*          qp   = (float*)(wsb + 8388608);
    float*          kp   = (float*)(wsb + 16777216);
    float*          vp   = (float*)(wsb + 25165824);
    unsigned short* attb = (unsigned short*)(wsb + 33554432);
    unsigned short* Xb   = (unsigned short*)(wsb + 37748736);
    float*          S    = (float*)(wsb + 37748736);
    float*          z    = (float*)(wsb + 46137344);

    dim3 blk(256);
    convert_kernel<<<dim3(2048, 7), blk, 0, stream>>>(
        query, key_, value, Wq, Wk, Wv, Wo, Xb, Wb);
    proj_bf16_kernel<<<dim3(DMODEL / 128, M / 64, 3), blk, 0, stream>>>(
        Xb, Wb, qp, kp, vp);
    chunk_kv_kernel<<<dim3(NC, BH), blk, 0, stream>>>(kp, vp, S, z, NC);
    prefix_kernel<<<dim3(BH * 16), blk, 0, stream>>>(S, z, NC);
    attn_chunk_kernel<<<dim3(NC, BH), blk, 0, stream>>>(qp, kp, vp, S, z, attb, NC);
    gemm_out_bf16_kernel<<<dim3(DMODEL / 128, M / 64), blk, 0, stream>>>(
        attb, Wb + 3 * (size_t)DMODEL * DMODEL, out);
}